// Round 11
// baseline (74.226 us; speedup 1.0000x reference)
//
#include <hip/hip_runtime.h>
#include <hip/hip_bf16.h>

typedef __attribute__((ext_vector_type(8))) short bf16x8;
typedef __attribute__((ext_vector_type(4))) float f32x4;
typedef __attribute__((ext_vector_type(2))) float f32x2;

#define ND 32    // feature dim (independent LSTMs)
#define NH 64    // hidden
#define NB 128   // batch
#define NT 128   // time
#define NG 256   // 4*NH gates
#define BB 16    // batch rows per workgroup (batch = MFMA n-dim)
#define HSTR 72  // h ring row stride (elems): 144B, 16B-aligned rows
#define RDEP 8   // h ring depth; time loop unrolled by 8 -> static slots
#define SLOT (BB * HSTR)   // 1152 elems = 2304 B per ring slot
#define LOG2E 1.44269504f

__device__ __forceinline__ unsigned short f2bf(float f) {
    union { float f; unsigned u; } v; v.f = f;
    unsigned r = v.u + 0x7FFFu + ((v.u >> 16) & 1u);   // RNE
    return (unsigned short)(r >> 16);
}
// TRANS ops via compiler intrinsics ONLY (R2-R4 post-mortem: raw inline-asm
// v_exp/v_rcp hide the trans-result hazard from the backend -> schedule-
// dependent corruption. Intrinsics = backend owns hazard wait-states.)
__device__ __forceinline__ float fast_rcp(float x) {
    return __builtin_amdgcn_rcpf(x);
}
__device__ __forceinline__ float fast_exp2(float x) {   // 2^x
    return __builtin_amdgcn_exp2f(x);
}
__device__ __forceinline__ unsigned cvt_pk_bf16(float lo, float hi) {
    unsigned r; asm("v_cvt_pk_bf16_f32 %0, %1, %2" : "=v"(r) : "v"(lo), "v"(hi));
    return r;
}
__device__ __forceinline__ float bf_lo(unsigned u) {
    union { unsigned u; float f; } v; v.u = u << 16; return v.f;
}
__device__ __forceinline__ float bf_hi(unsigned u) {
    union { unsigned u; float f; } v; v.u = u & 0xffff0000u; return v.f;
}

// ---- 2-lane float helpers, PURE C ext-vector ops (clang lowers +,* to
// v_pk_{add,mul}_f32 on gfx950). Trans ops are scalar intrinsics per lane.
__device__ __forceinline__ f32x2 vfma(f32x2 a, f32x2 b, f32x2 c) {
    f32x2 r;
    r.x = __builtin_fmaf(a.x, b.x, c.x);
    r.y = __builtin_fmaf(a.y, b.y, c.y);
    return r;
}
__device__ __forceinline__ f32x2 vexp2(f32x2 v) {
    f32x2 r; r.x = fast_exp2(v.x); r.y = fast_exp2(v.y); return r;
}
__device__ __forceinline__ f32x2 vrcp(f32x2 v) {
    f32x2 r; r.x = fast_rcp(v.x); r.y = fast_rcp(v.y); return r;
}

__global__ __launch_bounds__(512) void lstm_imputer_kernel(
    const float* __restrict__ x_raw,
    const void*  __restrict__ mask_pad,
    const float* __restrict__ W_ih,
    const float* __restrict__ W_hh,
    const float* __restrict__ b_ih,
    const float* __restrict__ b_hh,
    const float* __restrict__ W_out,
    const float* __restrict__ b_out,
    float* __restrict__ out)
{
    const int d   = blockIdx.x;        // feature / LSTM index
    const int b0  = blockIdx.y * BB;   // batch block
    const int tid = threadIdx.x;
    const int w    = tid >> 6;         // wave 0..7 = 8-j tile index
    const int lane = tid & 63;
    const int grp  = lane >> 4;        // k-fragment group
    const int l16  = lane & 15;        // batch col (MFMA n) / A row slot

    // NON-REDUNDANT gate packing (R7): each wave owns j = w*8..w*8+7 and
    // packs TWO gate types per MFMA A-tile, row m = (j_local<<1)|gate.
    // Every lane holds i,f,g,o for its 2 j's -> 6 MFMA/wave/step.

    // x_lds[t][b][32] bf16; XOR swizzle = b-swz ^ t-swz (R10).
    __shared__ alignas(16) unsigned short x_lds[(NT + 1) * BB * 32]; // 129 KB
    __shared__ alignas(16) unsigned short h_ring[RDEP][SLOT];        // 18 KB
    __shared__ int flag_sh;

    // ---------------- preamble ----------------
    if (tid == 0) flag_sh = 0;
    for (int e = tid; e < SLOT; e += 512) h_ring[RDEP - 1][e] = 0; // h(-1)=0
    // zero the x pad step
    x_lds[NT * BB * 32 + tid] = 0;

    // detect mask dtype: int32 {0,1} words are all <=1; byte-bools give words >1
    {
        const unsigned* mw = (const unsigned*)mask_pad;
        int f = 0;
        for (int e = tid; e < (NB * NT) / 4; e += 512) f |= (mw[e] > 1u) ? 1 : 0;
        if (f) atomicOr(&flag_sh, 1);
    }
    __syncthreads();
    const bool byteMode = (flag_sh != 0);

    // stage x (masked, bf16) into swizzled LDS: 16B writes, 16 iters/thread
    {
        const unsigned char* mb = (const unsigned char*)mask_pad;
        const int* mi = (const int*)mask_pad;
        #pragma unroll 4
        for (int it = 0; it < 16; ++it) {
            int u  = tid + it * 512;         // [b][t][k8] 8-elem block index
            int k8 = (u & 3) * 8;
            int t  = (u >> 2) & (NT - 1);
            int b  = u >> 9;
            bool mk = byteMode ? (mb[(b0 + b) * NT + t] != 0)
                               : (mi[(b0 + b) * NT + t] != 0);
            const float* src = x_raw + ((size_t)(b0 + b) * NT + t) * ND + k8;
            f32x4 xv0 = *(const f32x4*)(src);
            f32x4 xv1 = *(const f32x4*)(src + 4);
            uint4 pk = make_uint4(0, 0, 0, 0);
            if (mk) {
                pk.x = cvt_pk_bf16(xv0[0], xv0[1]);
                pk.y = cvt_pk_bf16(xv0[2], xv0[3]);
                pk.z = cvt_pk_bf16(xv1[0], xv1[1]);
                pk.w = cvt_pk_bf16(xv1[2], xv1[3]);
            }
            int eo = (t * (BB * 32) + b * 32 + k8)
                     ^ (((b >> 2) & 3) << 3) ^ ((t & 7) << 3);
            *(uint4*)&x_lds[eo] = pk;
        }
    }

    // ---- weight A-fragments in registers (loop-invariant) ----
    // group 0 = {i,f} (gate base 0/64), group 1 = {g,o} (base 128/192).
    // A row slot s = l16 holds W row ga = g2*128 + (s&1)*64 + w*8 + (s>>1).
    bf16x8 aW0[2], aW1[2], aX[2];
    f32x4 cinit[2];
    {
        const float* Whh = W_hh + (size_t)d * NG * NH;
        const float* Wih = W_ih + (size_t)d * NG * (ND - 1);
        #pragma unroll
        for (int g2 = 0; g2 < 2; ++g2) {
            int ga = g2 * 128 + (l16 & 1) * 64 + w * 8 + (l16 >> 1);
            f32x4 wa = *(const f32x4*)(Whh + ga * NH + grp * 8);
            f32x4 wb = *(const f32x4*)(Whh + ga * NH + grp * 8 + 4);
            f32x4 wc = *(const f32x4*)(Whh + ga * NH + 32 + grp * 8);
            f32x4 wd = *(const f32x4*)(Whh + ga * NH + 32 + grp * 8 + 4);
            #pragma unroll
            for (int e = 0; e < 4; ++e) {
                aW0[g2][e]     = (short)f2bf(wa[e]);
                aW0[g2][e + 4] = (short)f2bf(wb[e]);
                aW1[g2][e]     = (short)f2bf(wc[e]);
                aW1[g2][e + 4] = (short)f2bf(wd[e]);
            }
            #pragma unroll
            for (int e = 0; e < 8; ++e) {
                int j = grp * 8 + e;
                float vv = 0.0f;
                if (j != d) vv = Wih[ga * (ND - 1) + (j < d ? j : j - 1)];
                aX[g2][e] = (short)f2bf(vv);
            }
            // C-init: comp reg -> C row m = grp*4+reg -> gate row gr
            #pragma unroll
            for (int reg = 0; reg < 4; ++reg) {
                int m  = grp * 4 + reg;
                int gr = g2 * 128 + (m & 1) * 64 + w * 8 + (m >> 1);
                cinit[g2][reg] = b_ih[d * NG + gr] + b_hh[d * NG + gr];
            }
        }
    }
    const f32x4 kZ4 = {0.f, 0.f, 0.f, 0.f};

    // packed-activation constants (register pairs, loop-invariant)
    // c'-prescale (R10): cell state kept as c' = 2*LOG2E*c, eC = exp2(c').
    const f32x2 kONE = {1.f, 1.f};
    const f32x2 kNL  = {-LOG2E, -LOG2E};
    const f32x2 kTL  = {2.0f * LOG2E, 2.0f * LOG2E};
    const f32x2 kN4L = {-4.0f * LOG2E, -4.0f * LOG2E};
    const f32x2 kN2  = {-2.f, -2.f};

    // flush-role constants: thread handles (ta_off, b, j-group of 8)
    const int f_ta = tid >> 7;          // 0..3
    const int f_b  = (tid >> 3) & 15;   // batch row
    const int f_jg = tid & 7;           // j-group
    float wout8[8];
    #pragma unroll
    for (int k = 0; k < 8; ++k) wout8[k] = W_out[d * NH + f_jg * 8 + k];
    const float bout = b_out[d];

    // ---- loop-invariant LDS/global pointers ----
    const unsigned short* hrd = &h_ring[0][l16 * HSTR + grp * 8];          // + slot*SLOT
    // this lane produces h for j = w*8 + 2*grp + {0,1} (from acc comps)
    unsigned short*       hwr = &h_ring[0][l16 * HSTR + w * 8 + grp * 2];
    // x read base (elem index, pre-b-swz); t-swz applied per STEP (static)
    const int xbase = (l16 * 32 + grp * 8) ^ (((l16 >> 2) & 3) << 3);
    const unsigned short* xl  = x_lds;                                     // + tb*512
    const unsigned short* fp0 = &h_ring[4][f_b * HSTR + f_jg * 8];         // slots 4..7
    const unsigned short* fp1 = &h_ring[0][f_b * HSTR + f_jg * 8];         // slots 0..3
    float* outp = out + ((size_t)(b0 + f_b) * NT + f_ta) * ND + d;         // + ta0*ND

    f32x2 cpair = {0.f, 0.f};  // PRESCALED cell state c' = 2L*c
    uint4 fpre;                // FLUSH pre-read buffer (R11: read 1 step early)

    __syncthreads();   // x_lds + h_ring init ready (one-time full drain)

    // x-fragment register prefetch for step 0 (t=0: t-swz = 0)
    bf16x8 bxp = *(const bf16x8*)(xl + xbase);

// output projection from the pre-read register (R11): pure compute in the
// ds_read window — no LDS read latency at the point of use.
#define FLUSHR(TA0)                                                           \
    do {                                                                      \
        float p;                                                              \
        p = bf_lo(fpre.x) * wout8[0];                                        \
        p = __builtin_fmaf(bf_hi(fpre.x), wout8[1], p);                      \
        p = __builtin_fmaf(bf_lo(fpre.y), wout8[2], p);                      \
        p = __builtin_fmaf(bf_hi(fpre.y), wout8[3], p);                      \
        p = __builtin_fmaf(bf_lo(fpre.z), wout8[4], p);                      \
        p = __builtin_fmaf(bf_hi(fpre.z), wout8[5], p);                      \
        p = __builtin_fmaf(bf_lo(fpre.w), wout8[6], p);                      \
        p = __builtin_fmaf(bf_hi(fpre.w), wout8[7], p);                      \
        p += __shfl_xor(p, 1);                                               \
        p += __shfl_xor(p, 2);                                               \
        p += __shfl_xor(p, 4);                                               \
        if (f_jg == 0) outp[(size_t)(TA0) * ND] = p + bout;                  \
    } while (0)

// Step schedule (R7/R10-proven): issue h-reads (bh1 first), fill the LDS
// read window with FLUSHR (U==3/7, register-based) and the 2 all-register
// x-part MFMAs. R11 split-K: the aW1 chain carries (cinit + x + W1*h1);
// an INDEPENDENT bif/bgo = W0*h0 pair starts from zero; merged by pk_add
// at gate extraction -> one less MFMA latency on the recurrence path.
// FLUSH data for steps 3/7 is pre-read at steps 2/6 (slots ≥3 barriers old,
// overwritten only after use -> race-free; drained by each step's lgkmcnt).
#define STEP(U)                                                               \
    do {                                                                      \
        const bf16x8 bh1 = *(const bf16x8*)(hrd + (((U) + 7) & 7) * SLOT + 32);\
        const bf16x8 bh0 = *(const bf16x8*)(hrd + (((U) + 7) & 7) * SLOT);    \
        if ((U) == 2) fpre = *(const uint4*)(fp0 + f_ta * SLOT);              \
        if ((U) == 6) fpre = *(const uint4*)(fp1 + f_ta * SLOT);              \
        if ((U) == 3) { if (tb > 0) FLUSHR(tb - 4); }                         \
        if ((U) == 7) { FLUSHR(tb); }                                         \
        f32x4 aif, ago, bif, bgo;                                             \
        aif = __builtin_amdgcn_mfma_f32_16x16x32_bf16(aX[0], bxp, cinit[0], 0, 0, 0); \
        ago = __builtin_amdgcn_mfma_f32_16x16x32_bf16(aX[1], bxp, cinit[1], 0, 0, 0); \
        aif = __builtin_amdgcn_mfma_f32_16x16x32_bf16(aW1[0], bh1, aif, 0, 0, 0); \
        ago = __builtin_amdgcn_mfma_f32_16x16x32_bf16(aW1[1], bh1, ago, 0, 0, 0); \
        bif = __builtin_amdgcn_mfma_f32_16x16x32_bf16(aW0[0], bh0, kZ4, 0, 0, 0); \
        bgo = __builtin_amdgcn_mfma_f32_16x16x32_bf16(aW0[1], bh0, kZ4, 0, 0, 0); \
        bxp = *(const bf16x8*)(xl + ((U) + 1) * 512                           \
                               + (xbase ^ (((((U) + 1)) & 7) << 3)));         \
        /* gate extraction + split-K merge: comps {0,2}=(j0,j1) gate A,      \
           {1,3}=gate B; sum order ((cinit+x)+W1h)+W0h */                     \
        f32x2 I = __builtin_shufflevector(aif, aif, 0, 2)                     \
                + __builtin_shufflevector(bif, bif, 0, 2);                    \
        f32x2 F = __builtin_shufflevector(aif, aif, 1, 3)                     \
                + __builtin_shufflevector(bif, bif, 1, 3);                    \
        f32x2 G = __builtin_shufflevector(ago, ago, 0, 2)                     \
                + __builtin_shufflevector(bgo, bgo, 0, 2);                    \
        f32x2 O = __builtin_shufflevector(ago, ago, 1, 3)                     \
                + __builtin_shufflevector(bgo, bgo, 1, 3);                    \
        f32x2 eI = vexp2(kNL * I);                                            \
        f32x2 eF = vexp2(kNL * F);                                            \
        f32x2 eG = vexp2(kTL * G);                                            \
        f32x2 eO = vexp2(kNL * O);                                            \
        f32x2 Av = kONE + eI, Bv = kONE + eF;                                 \
        f32x2 Cv = kONE + eG, Dv = kONE + eO;                                 \
        f32x2 AB = Av * Bv, CD = Cv * Dv;                                     \
        f32x2 rab = vrcp(AB), rcd = vrcp(CD);                                 \
        f32x2 iv = rab * Bv, ff = rab * Av;                                   \
        /* tg2 = 2L*tanh(g) = fma(-4L, rcd*Dv, 2L): prescaled by 2L */        \
        f32x2 tg2 = vfma(kN4L, rcd * Dv, kTL);                                \
        f32x2 ov = rcd * Cv;                                                  \
        cpair = vfma(ff, cpair, iv * tg2);   /* c' = 2L*c */                  \
        f32x2 eC = vexp2(cpair);             /* exp2(2L*c) directly */        \
        f32x2 hv = ov * vfma(kN2, vrcp(kONE + eC), kONE);                     \
        *(unsigned*)(hwr + (U) * SLOT) = cvt_pk_bf16(hv.x, hv.y);             \
        asm volatile("s_waitcnt lgkmcnt(0)\n\ts_barrier" ::: "memory");       \
    } while (0)

    // ---------------- time loop: 16 outer iters x 8 static steps ----------
    for (int tb = 0; tb < NT; tb += 8) {
        STEP(0); STEP(1); STEP(2); STEP(3);
        STEP(4); STEP(5); STEP(6); STEP(7);
        xl += 8 * 512;
    }

    // epilogue flush: ta in [NT-4, NT-1] (slots 4..7; final barrier drained)
    {
        fpre = *(const uint4*)(fp0 + f_ta * SLOT);
        FLUSHR(NT - 4);
    }
#undef STEP
#undef FLUSHR
}

extern "C" void kernel_launch(void* const* d_in, const int* in_sizes, int n_in,
                              void* d_out, int out_size, void* d_ws, size_t ws_size,
                              hipStream_t stream) {
    const float* x_raw   = (const float*)d_in[0];
    const void*  mask_pad = d_in[1];
    const float* W_ih    = (const float*)d_in[2];
    const float* W_hh    = (const float*)d_in[3];
    const float* b_ih    = (const float*)d_in[4];
    const float* b_hh    = (const float*)d_in[5];
    const float* W_out   = (const float*)d_in[6];
    const float* b_out   = (const float*)d_in[7];
    float* out = (float*)d_out;

    dim3 grid(ND, NB / BB);
    lstm_imputer_kernel<<<grid, 512, 0, stream>>>(
        x_raw, mask_pad, W_ih, W_hh, b_ih, b_hh, W_out, b_out, out);
}

// Round 12
// 72.014 us; speedup vs baseline: 1.0307x; 1.0307x over previous
//
#include <hip/hip_runtime.h>
#include <hip/hip_bf16.h>

typedef __attribute__((ext_vector_type(8))) short bf16x8;
typedef __attribute__((ext_vector_type(4))) float f32x4;
typedef __attribute__((ext_vector_type(2))) float f32x2;

#define ND 32    // feature dim (independent LSTMs)
#define NH 64    // hidden
#define NB 128   // batch
#define NT 128   // time
#define NG 256   // 4*NH gates
#define BB 16    // batch rows per workgroup (batch = MFMA n-dim)
#define HSTR 72  // h ring row stride (elems): 144B, 16B-aligned rows
#define RDEP 8   // h ring depth; time loop unrolled by 8 -> static slots
#define SLOT (BB * HSTR)   // 1152 elems = 2304 B per ring slot
#define LOG2E 1.44269504f

__device__ __forceinline__ unsigned short f2bf(float f) {
    union { float f; unsigned u; } v; v.f = f;
    unsigned r = v.u + 0x7FFFu + ((v.u >> 16) & 1u);   // RNE
    return (unsigned short)(r >> 16);
}
// TRANS ops via compiler intrinsics ONLY (R2-R4 post-mortem: raw inline-asm
// v_exp/v_rcp hide the trans-result hazard from the backend -> schedule-
// dependent corruption. Intrinsics = backend owns hazard wait-states.)
__device__ __forceinline__ float fast_rcp(float x) {
    return __builtin_amdgcn_rcpf(x);
}
__device__ __forceinline__ float fast_exp2(float x) {   // 2^x
    return __builtin_amdgcn_exp2f(x);
}
__device__ __forceinline__ unsigned cvt_pk_bf16(float lo, float hi) {
    unsigned r; asm("v_cvt_pk_bf16_f32 %0, %1, %2" : "=v"(r) : "v"(lo), "v"(hi));
    return r;
}
__device__ __forceinline__ float bf_lo(unsigned u) {
    union { unsigned u; float f; } v; v.u = u << 16; return v.f;
}
__device__ __forceinline__ float bf_hi(unsigned u) {
    union { unsigned u; float f; } v; v.u = u & 0xffff0000u; return v.f;
}

// ---- 2-lane float helpers, PURE C ext-vector ops (clang lowers +,* to
// v_pk_{add,mul}_f32 on gfx950). Trans ops are scalar intrinsics per lane.
__device__ __forceinline__ f32x2 vfma(f32x2 a, f32x2 b, f32x2 c) {
    f32x2 r;
    r.x = __builtin_fmaf(a.x, b.x, c.x);
    r.y = __builtin_fmaf(a.y, b.y, c.y);
    return r;
}
__device__ __forceinline__ f32x2 vexp2(f32x2 v) {
    f32x2 r; r.x = fast_exp2(v.x); r.y = fast_exp2(v.y); return r;
}
__device__ __forceinline__ f32x2 vrcp(f32x2 v) {
    f32x2 r; r.x = fast_rcp(v.x); r.y = fast_rcp(v.y); return r;
}

__global__ __launch_bounds__(512) void lstm_imputer_kernel(
    const float* __restrict__ x_raw,
    const void*  __restrict__ mask_pad,
    const float* __restrict__ W_ih,
    const float* __restrict__ W_hh,
    const float* __restrict__ b_ih,
    const float* __restrict__ b_hh,
    const float* __restrict__ W_out,
    const float* __restrict__ b_out,
    float* __restrict__ out)
{
    const int d   = blockIdx.x;        // feature / LSTM index
    const int b0  = blockIdx.y * BB;   // batch block
    const int tid = threadIdx.x;
    const int w    = tid >> 6;         // wave 0..7 = 8-j tile index
    const int lane = tid & 63;
    const int grp  = lane >> 4;        // k-fragment group
    const int l16  = lane & 15;        // batch col (MFMA n) / A row slot

    // NON-REDUNDANT gate packing (R7): each wave owns j = w*8..w*8+7 and
    // packs TWO gate types per MFMA A-tile, row m = (j_local<<1)|gate.
    // Every lane holds i,f,g,o for its 2 j's -> 6 MFMA/wave/step.
    // R11 lesson: MFMA C-chaining is full-rate on CDNA -> keep the single
    // chained x->W1->W0 accumulator (split-K merge only adds VALU issue).

    // x_lds[t][b][32] bf16; XOR swizzle = b-swz ^ t-swz (R10).
    __shared__ alignas(16) unsigned short x_lds[(NT + 1) * BB * 32]; // 129 KB
    __shared__ alignas(16) unsigned short h_ring[RDEP][SLOT];        // 18 KB
    __shared__ int flag_sh;

    // ---------------- preamble ----------------
    if (tid == 0) flag_sh = 0;
    for (int e = tid; e < SLOT; e += 512) h_ring[RDEP - 1][e] = 0; // h(-1)=0
    // zero the x pad step
    x_lds[NT * BB * 32 + tid] = 0;

    // detect mask dtype: int32 {0,1} words are all <=1; byte-bools give words >1
    {
        const unsigned* mw = (const unsigned*)mask_pad;
        int f = 0;
        for (int e = tid; e < (NB * NT) / 4; e += 512) f |= (mw[e] > 1u) ? 1 : 0;
        if (f) atomicOr(&flag_sh, 1);
    }
    __syncthreads();
    const bool byteMode = (flag_sh != 0);

    // stage x (masked, bf16) into swizzled LDS: 16B writes, 16 iters/thread
    {
        const unsigned char* mb = (const unsigned char*)mask_pad;
        const int* mi = (const int*)mask_pad;
        #pragma unroll 4
        for (int it = 0; it < 16; ++it) {
            int u  = tid + it * 512;         // [b][t][k8] 8-elem block index
            int k8 = (u & 3) * 8;
            int t  = (u >> 2) & (NT - 1);
            int b  = u >> 9;
            bool mk = byteMode ? (mb[(b0 + b) * NT + t] != 0)
                               : (mi[(b0 + b) * NT + t] != 0);
            const float* src = x_raw + ((size_t)(b0 + b) * NT + t) * ND + k8;
            f32x4 xv0 = *(const f32x4*)(src);
            f32x4 xv1 = *(const f32x4*)(src + 4);
            uint4 pk = make_uint4(0, 0, 0, 0);
            if (mk) {
                pk.x = cvt_pk_bf16(xv0[0], xv0[1]);
                pk.y = cvt_pk_bf16(xv0[2], xv0[3]);
                pk.z = cvt_pk_bf16(xv1[0], xv1[1]);
                pk.w = cvt_pk_bf16(xv1[2], xv1[3]);
            }
            int eo = (t * (BB * 32) + b * 32 + k8)
                     ^ (((b >> 2) & 3) << 3) ^ ((t & 7) << 3);
            *(uint4*)&x_lds[eo] = pk;
        }
    }

    // ---- weight A-fragments in registers (loop-invariant) ----
    // group 0 = {i,f} (gate base 0/64), group 1 = {g,o} (base 128/192).
    // A row slot s = l16 holds W row ga = g2*128 + (s&1)*64 + w*8 + (s>>1).
    bf16x8 aW0[2], aW1[2], aX[2];
    f32x4 cinit[2];
    {
        const float* Whh = W_hh + (size_t)d * NG * NH;
        const float* Wih = W_ih + (size_t)d * NG * (ND - 1);
        #pragma unroll
        for (int g2 = 0; g2 < 2; ++g2) {
            int ga = g2 * 128 + (l16 & 1) * 64 + w * 8 + (l16 >> 1);
            f32x4 wa = *(const f32x4*)(Whh + ga * NH + grp * 8);
            f32x4 wb = *(const f32x4*)(Whh + ga * NH + grp * 8 + 4);
            f32x4 wc = *(const f32x4*)(Whh + ga * NH + 32 + grp * 8);
            f32x4 wd = *(const f32x4*)(Whh + ga * NH + 32 + grp * 8 + 4);
            #pragma unroll
            for (int e = 0; e < 4; ++e) {
                aW0[g2][e]     = (short)f2bf(wa[e]);
                aW0[g2][e + 4] = (short)f2bf(wb[e]);
                aW1[g2][e]     = (short)f2bf(wc[e]);
                aW1[g2][e + 4] = (short)f2bf(wd[e]);
            }
            #pragma unroll
            for (int e = 0; e < 8; ++e) {
                int j = grp * 8 + e;
                float vv = 0.0f;
                if (j != d) vv = Wih[ga * (ND - 1) + (j < d ? j : j - 1)];
                aX[g2][e] = (short)f2bf(vv);
            }
            // C-init: comp reg -> C row m = grp*4+reg -> gate row gr
            #pragma unroll
            for (int reg = 0; reg < 4; ++reg) {
                int m  = grp * 4 + reg;
                int gr = g2 * 128 + (m & 1) * 64 + w * 8 + (m >> 1);
                cinit[g2][reg] = b_ih[d * NG + gr] + b_hh[d * NG + gr];
            }
        }
    }

    // packed-activation constants (register pairs, loop-invariant)
    // c'-prescale (R10): cell state kept as c' = 2*LOG2E*c, eC = exp2(c').
    const f32x2 kONE = {1.f, 1.f};
    const f32x2 kNL  = {-LOG2E, -LOG2E};
    const f32x2 kTL  = {2.0f * LOG2E, 2.0f * LOG2E};
    const f32x2 kN4L = {-4.0f * LOG2E, -4.0f * LOG2E};
    const f32x2 kN2  = {-2.f, -2.f};

    // flush-role constants: thread handles (ta_off, b, j-group of 8)
    const int f_ta = tid >> 7;          // 0..3
    const int f_b  = (tid >> 3) & 15;   // batch row
    const int f_jg = tid & 7;           // j-group
    float wout8[8];
    #pragma unroll
    for (int k = 0; k < 8; ++k) wout8[k] = W_out[d * NH + f_jg * 8 + k];
    const float bout = b_out[d];

    // ---- loop-invariant LDS/global pointers ----
    const unsigned short* hrd = &h_ring[0][l16 * HSTR + grp * 8];          // + slot*SLOT
    // this lane produces h for j = w*8 + 2*grp + {0,1} (from acc comps)
    unsigned short*       hwr = &h_ring[0][l16 * HSTR + w * 8 + grp * 2];
    // x read base (elem index, pre-b-swz); t-swz applied per STEP (static)
    const int xbase = (l16 * 32 + grp * 8) ^ (((l16 >> 2) & 3) << 3);
    const unsigned short* xl  = x_lds;                                     // + tb*512
    const unsigned short* fp0 = &h_ring[4][f_b * HSTR + f_jg * 8];         // slots 4..7
    const unsigned short* fp1 = &h_ring[0][f_b * HSTR + f_jg * 8];         // slots 0..3
    float* outp = out + ((size_t)(b0 + f_b) * NT + f_ta) * ND + d;         // + ta0*ND

    f32x2 cpair = {0.f, 0.f};  // PRESCALED cell state c' = 2L*c
    uint4 fpre;                // FLUSH pre-read buffer (R12: read 1 step early)

    __syncthreads();   // x_lds + h_ring init ready (one-time full drain)

    // x-fragment register prefetch for step 0 (t=0: t-swz = 0)
    bf16x8 bxp = *(const bf16x8*)(xl + xbase);

// output projection from the pre-read register (R12): pure compute in the
// ds_read window — no LDS read latency at the point of use.
#define FLUSHR(TA0)                                                           \
    do {                                                                      \
        float p;                                                              \
        p = bf_lo(fpre.x) * wout8[0];                                        \
        p = __builtin_fmaf(bf_hi(fpre.x), wout8[1], p);                      \
        p = __builtin_fmaf(bf_lo(fpre.y), wout8[2], p);                      \
        p = __builtin_fmaf(bf_hi(fpre.y), wout8[3], p);                      \
        p = __builtin_fmaf(bf_lo(fpre.z), wout8[4], p);                      \
        p = __builtin_fmaf(bf_hi(fpre.z), wout8[5], p);                      \
        p = __builtin_fmaf(bf_lo(fpre.w), wout8[6], p);                      \
        p = __builtin_fmaf(bf_hi(fpre.w), wout8[7], p);                      \
        p += __shfl_xor(p, 1);                                               \
        p += __shfl_xor(p, 2);                                               \
        p += __shfl_xor(p, 4);                                               \
        if (f_jg == 0) outp[(size_t)(TA0) * ND] = p + bout;                  \
    } while (0)

// Step schedule (R10-proven core): issue h-reads (bh1 first), fill the LDS
// read window with FLUSHR (U==3/7, register-based) and the 2 all-register
// x-part MFMAs; gate MFMAs C-chain (full-rate) onto the x accumulators.
// FLUSH data for steps 3/7 is pre-read at steps 2/6 (slots >=3 barriers old,
// overwritten only after use -> race-free; drained by each step's lgkmcnt).
#define STEP(U)                                                               \
    do {                                                                      \
        const bf16x8 bh1 = *(const bf16x8*)(hrd + (((U) + 7) & 7) * SLOT + 32);\
        const bf16x8 bh0 = *(const bf16x8*)(hrd + (((U) + 7) & 7) * SLOT);    \
        if ((U) == 2) fpre = *(const uint4*)(fp0 + f_ta * SLOT);              \
        if ((U) == 6) fpre = *(const uint4*)(fp1 + f_ta * SLOT);              \
        if ((U) == 3) { if (tb > 0) FLUSHR(tb - 4); }                         \
        if ((U) == 7) { FLUSHR(tb); }                                         \
        f32x4 aif, ago;                                                       \
        aif = __builtin_amdgcn_mfma_f32_16x16x32_bf16(aX[0], bxp, cinit[0], 0, 0, 0); \
        ago = __builtin_amdgcn_mfma_f32_16x16x32_bf16(aX[1], bxp, cinit[1], 0, 0, 0); \
        aif = __builtin_amdgcn_mfma_f32_16x16x32_bf16(aW1[0], bh1, aif, 0, 0, 0); \
        ago = __builtin_amdgcn_mfma_f32_16x16x32_bf16(aW1[1], bh1, ago, 0, 0, 0); \
        aif = __builtin_amdgcn_mfma_f32_16x16x32_bf16(aW0[0], bh0, aif, 0, 0, 0); \
        ago = __builtin_amdgcn_mfma_f32_16x16x32_bf16(aW0[1], bh0, ago, 0, 0, 0); \
        bxp = *(const bf16x8*)(xl + ((U) + 1) * 512                           \
                               + (xbase ^ (((((U) + 1)) & 7) << 3)));         \
        /* gate extraction: comps {0,2} = (j0,j1) gate A, {1,3} = gate B */   \
        f32x2 I = __builtin_shufflevector(aif, aif, 0, 2);                    \
        f32x2 F = __builtin_shufflevector(aif, aif, 1, 3);                    \
        f32x2 G = __builtin_shufflevector(ago, ago, 0, 2);                    \
        f32x2 O = __builtin_shufflevector(ago, ago, 1, 3);                    \
        f32x2 eI = vexp2(kNL * I);                                            \
        f32x2 eF = vexp2(kNL * F);                                            \
        f32x2 eG = vexp2(kTL * G);                                            \
        f32x2 eO = vexp2(kNL * O);                                            \
        f32x2 Av = kONE + eI, Bv = kONE + eF;                                 \
        f32x2 Cv = kONE + eG, Dv = kONE + eO;                                 \
        f32x2 AB = Av * Bv, CD = Cv * Dv;                                     \
        f32x2 rab = vrcp(AB), rcd = vrcp(CD);                                 \
        f32x2 iv = rab * Bv, ff = rab * Av;                                   \
        /* tg2 = 2L*tanh(g) = fma(-4L, rcd*Dv, 2L): prescaled by 2L */        \
        f32x2 tg2 = vfma(kN4L, rcd * Dv, kTL);                                \
        f32x2 ov = rcd * Cv;                                                  \
        cpair = vfma(ff, cpair, iv * tg2);   /* c' = 2L*c */                  \
        f32x2 eC = vexp2(cpair);             /* exp2(2L*c) directly */        \
        f32x2 hv = ov * vfma(kN2, vrcp(kONE + eC), kONE);                     \
        *(unsigned*)(hwr + (U) * SLOT) = cvt_pk_bf16(hv.x, hv.y);             \
        asm volatile("s_waitcnt lgkmcnt(0)\n\ts_barrier" ::: "memory");       \
    } while (0)

    // ---------------- time loop: 16 outer iters x 8 static steps ----------
    for (int tb = 0; tb < NT; tb += 8) {
        STEP(0); STEP(1); STEP(2); STEP(3);
        STEP(4); STEP(5); STEP(6); STEP(7);
        xl += 8 * 512;
    }

    // epilogue flush: ta in [NT-4, NT-1] (slots 4..7; final barrier drained)
    {
        fpre = *(const uint4*)(fp0 + f_ta * SLOT);
        FLUSHR(NT - 4);
    }
#undef STEP
#undef FLUSHR
}

extern "C" void kernel_launch(void* const* d_in, const int* in_sizes, int n_in,
                              void* d_out, int out_size, void* d_ws, size_t ws_size,
                              hipStream_t stream) {
    const float* x_raw   = (const float*)d_in[0];
    const void*  mask_pad = d_in[1];
    const float* W_ih    = (const float*)d_in[2];
    const float* W_hh    = (const float*)d_in[3];
    const float* b_ih    = (const float*)d_in[4];
    const float* b_hh    = (const float*)d_in[5];
    const float* W_out   = (const float*)d_in[6];
    const float* b_out   = (const float*)d_in[7];
    float* out = (float*)d_out;

    dim3 grid(ND, NB / BB);
    lstm_imputer_kernel<<<grid, 512, 0, stream>>>(
        x_raw, mask_pad, W_ih, W_hh, b_ih, b_hh, W_out, b_out, out);
}

// Round 13
// 67.377 us; speedup vs baseline: 1.1016x; 1.0688x over previous
//
#include <hip/hip_runtime.h>
#include <hip/hip_bf16.h>

typedef __attribute__((ext_vector_type(8))) short bf16x8;
typedef __attribute__((ext_vector_type(4))) float f32x4;
typedef __attribute__((ext_vector_type(2))) float f32x2;

#define ND 32    // feature dim (independent LSTMs)
#define NH 64    // hidden
#define NB 128   // batch
#define NT 128   // time
#define NG 256   // 4*NH gates
#define BB 16    // batch rows per workgroup (batch = MFMA n-dim)
#define HSTR 72  // h ring row stride (elems): 144B, 16B-aligned rows
#define RDEP 8   // h ring depth; time loop unrolled by 8 -> static slots
#define SLOT (BB * HSTR)   // 1152 elems = 2304 B per ring slot
#define LOG2E 1.44269504f

__device__ __forceinline__ unsigned short f2bf(float f) {
    union { float f; unsigned u; } v; v.f = f;
    unsigned r = v.u + 0x7FFFu + ((v.u >> 16) & 1u);   // RNE
    return (unsigned short)(r >> 16);
}
// TRANS ops via compiler intrinsics ONLY (R2-R4 post-mortem: raw inline-asm
// v_exp/v_rcp hide the trans-result hazard from the backend -> schedule-
// dependent corruption. Intrinsics = backend owns hazard wait-states.)
__device__ __forceinline__ float fast_rcp(float x) {
    return __builtin_amdgcn_rcpf(x);
}
__device__ __forceinline__ float fast_exp2(float x) {   // 2^x
    return __builtin_amdgcn_exp2f(x);
}
__device__ __forceinline__ unsigned cvt_pk_bf16(float lo, float hi) {
    unsigned r; asm("v_cvt_pk_bf16_f32 %0, %1, %2" : "=v"(r) : "v"(lo), "v"(hi));
    return r;
}
__device__ __forceinline__ float bf_lo(unsigned u) {
    union { unsigned u; float f; } v; v.u = u << 16; return v.f;
}
__device__ __forceinline__ float bf_hi(unsigned u) {
    union { unsigned u; float f; } v; v.u = u & 0xffff0000u; return v.f;
}

// ---- 2-lane float helpers, PURE C ext-vector ops (clang lowers +,* to
// v_pk_{add,mul}_f32 on gfx950). Trans ops are scalar intrinsics per lane.
__device__ __forceinline__ f32x2 vfma(f32x2 a, f32x2 b, f32x2 c) {
    f32x2 r;
    r.x = __builtin_fmaf(a.x, b.x, c.x);
    r.y = __builtin_fmaf(a.y, b.y, c.y);
    return r;
}
__device__ __forceinline__ f32x2 vexp2(f32x2 v) {
    f32x2 r; r.x = fast_exp2(v.x); r.y = fast_exp2(v.y); return r;
}
__device__ __forceinline__ f32x2 vrcp(f32x2 v) {
    f32x2 r; r.x = fast_rcp(v.x); r.y = fast_rcp(v.y); return r;
}
__device__ __forceinline__ f32x2 lo2(f32x4 v) {
    return __builtin_shufflevector(v, v, 0, 1);   // sub-register alias
}
__device__ __forceinline__ f32x2 hi2(f32x4 v) {
    return __builtin_shufflevector(v, v, 2, 3);   // sub-register alias
}

__global__ __launch_bounds__(512) void lstm_imputer_kernel(
    const float* __restrict__ x_raw,
    const void*  __restrict__ mask_pad,
    const float* __restrict__ W_ih,
    const float* __restrict__ W_hh,
    const float* __restrict__ b_ih,
    const float* __restrict__ b_hh,
    const float* __restrict__ W_out,
    const float* __restrict__ b_out,
    float* __restrict__ out)
{
    const int d   = blockIdx.x;        // feature / LSTM index
    const int b0  = blockIdx.y * BB;   // batch block
    const int tid = threadIdx.x;
    const int w    = tid >> 6;         // wave 0..7 = 8-j tile index
    const int lane = tid & 63;
    const int grp  = lane >> 4;        // k-fragment group
    const int l16  = lane & 15;        // batch col (MFMA n) / A row slot

    // R13 gate packing: A-row m holds gate = (m>>1)&1, j_local =
    // (m&1)|((m>>2)<<1). Acc comps {0,1} = gateA(j0,j1), {2,3} = gateB(j0,j1)
    // -> extraction is consecutive-VGPR aliasing (zero v_mov for VOP3P).
    // R13 scale folding: rows pre-scaled by -L (i,f,o) / +2L (g) so MFMA
    // emits gates already in exp2 domain (deletes 4 pk_mul/lane/step).

    // x_lds[t][b][32] bf16; XOR swizzle = b-swz ^ t-swz (R10).
    __shared__ alignas(16) unsigned short x_lds[(NT + 1) * BB * 32]; // 129 KB
    __shared__ alignas(16) unsigned short h_ring[RDEP][SLOT];        // 18 KB
    __shared__ int flag_sh;

    // ---------------- preamble ----------------
    if (tid == 0) flag_sh = 0;
    for (int e = tid; e < SLOT; e += 512) h_ring[RDEP - 1][e] = 0; // h(-1)=0
    // zero the x pad step
    x_lds[NT * BB * 32 + tid] = 0;

    // detect mask dtype: int32 {0,1} words are all <=1; byte-bools give words >1
    {
        const unsigned* mw = (const unsigned*)mask_pad;
        int f = 0;
        for (int e = tid; e < (NB * NT) / 4; e += 512) f |= (mw[e] > 1u) ? 1 : 0;
        if (f) atomicOr(&flag_sh, 1);
    }
    __syncthreads();
    const bool byteMode = (flag_sh != 0);

    // stage x (masked, bf16) into swizzled LDS: 16B writes, 16 iters/thread
    {
        const unsigned char* mb = (const unsigned char*)mask_pad;
        const int* mi = (const int*)mask_pad;
        #pragma unroll 4
        for (int it = 0; it < 16; ++it) {
            int u  = tid + it * 512;         // [b][t][k8] 8-elem block index
            int k8 = (u & 3) * 8;
            int t  = (u >> 2) & (NT - 1);
            int b  = u >> 9;
            bool mk = byteMode ? (mb[(b0 + b) * NT + t] != 0)
                               : (mi[(b0 + b) * NT + t] != 0);
            const float* src = x_raw + ((size_t)(b0 + b) * NT + t) * ND + k8;
            f32x4 xv0 = *(const f32x4*)(src);
            f32x4 xv1 = *(const f32x4*)(src + 4);
            uint4 pk = make_uint4(0, 0, 0, 0);
            if (mk) {
                pk.x = cvt_pk_bf16(xv0[0], xv0[1]);
                pk.y = cvt_pk_bf16(xv0[2], xv0[3]);
                pk.z = cvt_pk_bf16(xv1[0], xv1[1]);
                pk.w = cvt_pk_bf16(xv1[2], xv1[3]);
            }
            int eo = (t * (BB * 32) + b * 32 + k8)
                     ^ (((b >> 2) & 3) << 3) ^ ((t & 7) << 3);
            *(uint4*)&x_lds[eo] = pk;
        }
    }

    // ---- weight A-fragments in registers (loop-invariant), R13 packing ----
    // group 0 = {i,f} (gate base 0/64), group 1 = {g,o} (base 128/192).
    // Row slot s = l16: gate = (s>>1)&1, j_local = (s&1)|((s>>2)<<1).
    // Rows pre-scaled: g-rows (ga in [128,192)) by +2L, others by -L.
    bf16x8 aW0[2], aW1[2], aX[2];
    f32x4 cinit[2];
    {
        const float* Whh = W_hh + (size_t)d * NG * NH;
        const float* Wih = W_ih + (size_t)d * NG * (ND - 1);
        const int gateS = (l16 >> 1) & 1;
        const int jlocS = (l16 & 1) | ((l16 >> 2) << 1);
        #pragma unroll
        for (int g2 = 0; g2 < 2; ++g2) {
            int ga = g2 * 128 + gateS * 64 + w * 8 + jlocS;
            float s = ((ga >> 6) == 2) ? 2.0f * LOG2E : -LOG2E;
            f32x4 wa = *(const f32x4*)(Whh + ga * NH + grp * 8);
            f32x4 wb = *(const f32x4*)(Whh + ga * NH + grp * 8 + 4);
            f32x4 wc = *(const f32x4*)(Whh + ga * NH + 32 + grp * 8);
            f32x4 wd = *(const f32x4*)(Whh + ga * NH + 32 + grp * 8 + 4);
            #pragma unroll
            for (int e = 0; e < 4; ++e) {
                aW0[g2][e]     = (short)f2bf(s * wa[e]);
                aW0[g2][e + 4] = (short)f2bf(s * wb[e]);
                aW1[g2][e]     = (short)f2bf(s * wc[e]);
                aW1[g2][e + 4] = (short)f2bf(s * wd[e]);
            }
            #pragma unroll
            for (int e = 0; e < 8; ++e) {
                int j = grp * 8 + e;
                float vv = 0.0f;
                if (j != d) vv = Wih[ga * (ND - 1) + (j < d ? j : j - 1)];
                aX[g2][e] = (short)f2bf(s * vv);
            }
            // C-init (bias, pre-scaled): comp reg -> C row m = grp*4+reg
            #pragma unroll
            for (int reg = 0; reg < 4; ++reg) {
                int m  = grp * 4 + reg;
                int gr = g2 * 128 + ((m >> 1) & 1) * 64 + w * 8
                         + ((m & 1) | ((m >> 2) << 1));
                float ss = ((gr >> 6) == 2) ? 2.0f * LOG2E : -LOG2E;
                cinit[g2][reg] = ss * (b_ih[d * NG + gr] + b_hh[d * NG + gr]);
            }
        }
    }

    // packed-activation constants (register pairs, loop-invariant)
    // c'-prescale (R10): cell state kept as c' = 2*LOG2E*c, eC = exp2(c').
    const f32x2 kONE = {1.f, 1.f};
    const f32x2 kTL  = {2.0f * LOG2E, 2.0f * LOG2E};
    const f32x2 kN4L = {-4.0f * LOG2E, -4.0f * LOG2E};
    const f32x2 kN2  = {-2.f, -2.f};

    // flush-role constants: thread handles (ta_off, b, j-group of 8)
    const int f_ta = tid >> 7;          // 0..3
    const int f_b  = (tid >> 3) & 15;   // batch row
    const int f_jg = tid & 7;           // j-group
    float wout8[8];
    #pragma unroll
    for (int k = 0; k < 8; ++k) wout8[k] = W_out[d * NH + f_jg * 8 + k];
    const float bout = b_out[d];

    // ---- loop-invariant LDS/global pointers ----
    const unsigned short* hrd = &h_ring[0][l16 * HSTR + grp * 8];          // + slot*SLOT
    // this lane produces h for j = w*8 + 2*grp + {0,1} (comps {0,1} of accs)
    unsigned short*       hwr = &h_ring[0][l16 * HSTR + w * 8 + grp * 2];
    // x read base (elem index, pre-b-swz); t-swz applied per STEP (static)
    const int xbase = (l16 * 32 + grp * 8) ^ (((l16 >> 2) & 3) << 3);
    const unsigned short* xl  = x_lds;                                     // + tb*512
    const unsigned short* fp0 = &h_ring[4][f_b * HSTR + f_jg * 8];         // slots 4..7
    const unsigned short* fp1 = &h_ring[0][f_b * HSTR + f_jg * 8];         // slots 0..3
    float* outp = out + ((size_t)(b0 + f_b) * NT + f_ta) * ND + d;         // + ta0*ND

    f32x2 cpair = {0.f, 0.f};  // PRESCALED cell state c' = 2L*c
    uint4 fpre;                // FLUSH pre-read buffer (R12: read 1 step early)

    __syncthreads();   // x_lds + h_ring init ready (one-time full drain)

    // x-fragment register prefetch for step 0 (t=0: t-swz = 0)
    bf16x8 bxp = *(const bf16x8*)(xl + xbase);

// output projection from the pre-read register (R12): pure compute in the
// ds_read window — no LDS read latency at the point of use.
#define FLUSHR(TA0)                                                           \
    do {                                                                      \
        float p;                                                              \
        p = bf_lo(fpre.x) * wout8[0];                                        \
        p = __builtin_fmaf(bf_hi(fpre.x), wout8[1], p);                      \
        p = __builtin_fmaf(bf_lo(fpre.y), wout8[2], p);                      \
        p = __builtin_fmaf(bf_hi(fpre.y), wout8[3], p);                      \
        p = __builtin_fmaf(bf_lo(fpre.z), wout8[4], p);                      \
        p = __builtin_fmaf(bf_hi(fpre.z), wout8[5], p);                      \
        p = __builtin_fmaf(bf_lo(fpre.w), wout8[6], p);                      \
        p = __builtin_fmaf(bf_hi(fpre.w), wout8[7], p);                      \
        p += __shfl_xor(p, 1);                                               \
        p += __shfl_xor(p, 2);                                               \
        p += __shfl_xor(p, 4);                                               \
        if (f_jg == 0) outp[(size_t)(TA0) * ND] = p + bout;                  \
    } while (0)

// Step schedule (R10/R12-proven): issue h-reads (bh1 first), fill the LDS
// read window with FLUSHR (U==3/7, register-based) and the 2 all-register
// x-part MFMAs; gate MFMAs C-chain (full-rate) onto the x accumulators.
// R13: gates emerge pre-scaled in exp2 domain; extraction is reg aliasing.
#define STEP(U)                                                               \
    do {                                                                      \
        const bf16x8 bh1 = *(const bf16x8*)(hrd + (((U) + 7) & 7) * SLOT + 32);\
        const bf16x8 bh0 = *(const bf16x8*)(hrd + (((U) + 7) & 7) * SLOT);    \
        if ((U) == 2) fpre = *(const uint4*)(fp0 + f_ta * SLOT);              \
        if ((U) == 6) fpre = *(const uint4*)(fp1 + f_ta * SLOT);              \
        if ((U) == 3) { if (tb > 0) FLUSHR(tb - 4); }                         \
        if ((U) == 7) { FLUSHR(tb); }                                         \
        f32x4 aif, ago;                                                       \
        aif = __builtin_amdgcn_mfma_f32_16x16x32_bf16(aX[0], bxp, cinit[0], 0, 0, 0); \
        ago = __builtin_amdgcn_mfma_f32_16x16x32_bf16(aX[1], bxp, cinit[1], 0, 0, 0); \
        aif = __builtin_amdgcn_mfma_f32_16x16x32_bf16(aW1[0], bh1, aif, 0, 0, 0); \
        ago = __builtin_amdgcn_mfma_f32_16x16x32_bf16(aW1[1], bh1, ago, 0, 0, 0); \
        aif = __builtin_amdgcn_mfma_f32_16x16x32_bf16(aW0[0], bh0, aif, 0, 0, 0); \
        ago = __builtin_amdgcn_mfma_f32_16x16x32_bf16(aW0[1], bh0, ago, 0, 0, 0); \
        bxp = *(const bf16x8*)(xl + ((U) + 1) * 512                           \
                               + (xbase ^ (((((U) + 1)) & 7) << 3)));         \
        /* extraction = consecutive-pair aliasing (R13 packing):             \
           aif = {-L*i(j0), -L*i(j1), -L*f(j0), -L*f(j1)},                   \
           ago = {2L*g(j0), 2L*g(j1), -L*o(j0), -L*o(j1)} */                 \
        f32x2 eI = vexp2(lo2(aif));                                           \
        f32x2 eF = vexp2(hi2(aif));                                           \
        f32x2 eG = vexp2(lo2(ago));                                           \
        f32x2 eO = vexp2(hi2(ago));                                           \
        f32x2 Av = kONE + eI, Bv = kONE + eF;                                 \
        f32x2 Cv = kONE + eG, Dv = kONE + eO;                                 \
        f32x2 AB = Av * Bv, CD = Cv * Dv;                                     \
        f32x2 rab = vrcp(AB), rcd = vrcp(CD);                                 \
        f32x2 iv = rab * Bv, ff = rab * Av;                                   \
        /* tg2 = 2L*tanh(g) = fma(-4L, 1/(1+eG), 2L); rcd*Dv = 1/(1+eG) */    \
        f32x2 tg2 = vfma(kN4L, rcd * Dv, kTL);                                \
        f32x2 ov = rcd * Cv;                                                  \
        cpair = vfma(ff, cpair, iv * tg2);   /* c' = 2L*c */                  \
        f32x2 eC = vexp2(cpair);             /* exp2(2L*c) directly */        \
        f32x2 hv = ov * vfma(kN2, vrcp(kONE + eC), kONE);                     \
        *(unsigned*)(hwr + (U) * SLOT) = cvt_pk_bf16(hv.x, hv.y);             \
        asm volatile("s_waitcnt lgkmcnt(0)\n\ts_barrier" ::: "memory");       \
    } while (0)

    // ---------------- time loop: 16 outer iters x 8 static steps ----------
    for (int tb = 0; tb < NT; tb += 8) {
        STEP(0); STEP(1); STEP(2); STEP(3);
        STEP(4); STEP(5); STEP(6); STEP(7);
        xl += 8 * 512;
    }

    // epilogue flush: ta in [NT-4, NT-1] (slots 4..7; final barrier drained)
    {
        fpre = *(const uint4*)(fp0 + f_ta * SLOT);
        FLUSHR(NT - 4);
    }
#undef STEP
#undef FLUSHR
}

extern "C" void kernel_launch(void* const* d_in, const int* in_sizes, int n_in,
                              void* d_out, int out_size, void* d_ws, size_t ws_size,
                              hipStream_t stream) {
    const float* x_raw   = (const float*)d_in[0];
    const void*  mask_pad = d_in[1];
    const float* W_ih    = (const float*)d_in[2];
    const float* W_hh    = (const float*)d_in[3];
    const float* b_ih    = (const float*)d_in[4];
    const float* b_hh    = (const float*)d_in[5];
    const float* W_out   = (const float*)d_in[6];
    const float* b_out   = (const float*)d_in[7];
    float* out = (float*)d_out;

    dim3 grid(ND, NB / BB);
    lstm_imputer_kernel<<<grid, 512, 0, stream>>>(
        x_raw, mask_pad, W_ih, W_hh, b_ih, b_hh, W_out, b_out, out);
}

// Round 14
// 65.801 us; speedup vs baseline: 1.1280x; 1.0240x over previous
//
#include <hip/hip_runtime.h>
#include <hip/hip_bf16.h>

typedef __attribute__((ext_vector_type(8))) short bf16x8;
typedef __attribute__((ext_vector_type(4))) float f32x4;
typedef __attribute__((ext_vector_type(2))) float f32x2;

#define ND 32    // feature dim (independent LSTMs)
#define NH 64    // hidden
#define NB 128   // batch
#define NT 128   // time
#define NG 256   // 4*NH gates
#define BB 16    // batch rows per workgroup (batch = MFMA n-dim)
#define HSTR 72  // h ring row stride (elems): 144B, 16B-aligned rows
#define RDEP 8   // h ring depth; time loop unrolled by 8 -> static slots
#define SLOT (BB * HSTR)   // 1152 elems = 2304 B per ring slot
#define LOG2E 1.44269504f

__device__ __forceinline__ unsigned short f2bf(float f) {
    union { float f; unsigned u; } v; v.f = f;
    unsigned r = v.u + 0x7FFFu + ((v.u >> 16) & 1u);   // RNE
    return (unsigned short)(r >> 16);
}
// TRANS ops via compiler intrinsics ONLY (R2-R4 post-mortem: raw inline-asm
// v_exp/v_rcp hide the trans-result hazard from the backend -> schedule-
// dependent corruption. Intrinsics = backend owns hazard wait-states.)
__device__ __forceinline__ float fast_rcp(float x) {
    return __builtin_amdgcn_rcpf(x);
}
__device__ __forceinline__ float fast_exp2(float x) {   // 2^x
    return __builtin_amdgcn_exp2f(x);
}
__device__ __forceinline__ unsigned cvt_pk_bf16(float lo, float hi) {
    unsigned r; asm("v_cvt_pk_bf16_f32 %0, %1, %2" : "=v"(r) : "v"(lo), "v"(hi));
    return r;
}
__device__ __forceinline__ float bf_lo(unsigned u) {
    union { unsigned u; float f; } v; v.u = u << 16; return v.f;
}
__device__ __forceinline__ float bf_hi(unsigned u) {
    union { unsigned u; float f; } v; v.u = u & 0xffff0000u; return v.f;
}
// DPP quad-local butterfly add (xor1 / xor2 within quads): pure VALU — no
// LDS traffic, bit-identical to __shfl_xor(p,1/2). (DPP was exonerated by
// R5/R6: the R2-era corruption was the inline-asm trans hazard.)
template<int CTRL>
__device__ __forceinline__ float dpp_addf(float p) {
    union { float f; int i; } s, r;
    s.f = p;
    r.i = __builtin_amdgcn_update_dpp(s.i, s.i, CTRL, 0xF, 0xF, false);
    return p + r.f;
}

// ---- 2-lane float helpers, PURE C ext-vector ops (clang lowers +,* to
// v_pk_{add,mul}_f32 on gfx950). Trans ops are scalar intrinsics per lane.
__device__ __forceinline__ f32x2 vfma(f32x2 a, f32x2 b, f32x2 c) {
    f32x2 r;
    r.x = __builtin_fmaf(a.x, b.x, c.x);
    r.y = __builtin_fmaf(a.y, b.y, c.y);
    return r;
}
__device__ __forceinline__ f32x2 vexp2(f32x2 v) {
    f32x2 r; r.x = fast_exp2(v.x); r.y = fast_exp2(v.y); return r;
}
__device__ __forceinline__ f32x2 vrcp(f32x2 v) {
    f32x2 r; r.x = fast_rcp(v.x); r.y = fast_rcp(v.y); return r;
}
__device__ __forceinline__ f32x2 lo2(f32x4 v) {
    return __builtin_shufflevector(v, v, 0, 1);   // sub-register alias
}
__device__ __forceinline__ f32x2 hi2(f32x4 v) {
    return __builtin_shufflevector(v, v, 2, 3);   // sub-register alias
}

__global__ __launch_bounds__(512) void lstm_imputer_kernel(
    const float* __restrict__ x_raw,
    const void*  __restrict__ mask_pad,
    const float* __restrict__ W_ih,
    const float* __restrict__ W_hh,
    const float* __restrict__ b_ih,
    const float* __restrict__ b_hh,
    const float* __restrict__ W_out,
    const float* __restrict__ b_out,
    float* __restrict__ out)
{
    const int d   = blockIdx.x;        // feature / LSTM index
    const int b0  = blockIdx.y * BB;   // batch block
    const int tid = threadIdx.x;
    const int w    = tid >> 6;         // wave 0..7 = 8-j tile index
    const int lane = tid & 63;
    const int grp  = lane >> 4;        // k-fragment group
    const int l16  = lane & 15;        // batch col (MFMA n) / A row slot

    // R13 gate packing: A-row m holds gate = (m>>1)&1, j_local =
    // (m&1)|((m>>2)<<1). Acc comps {0,1} = gateA(j0,j1), {2,3} = gateB(j0,j1)
    // -> extraction is consecutive-VGPR aliasing (zero v_mov for VOP3P).
    // R13 scale folding: rows pre-scaled by -L (i,f,o) / +2L (g) so MFMA
    // emits gates already in exp2 domain.

    // x_lds[t][b][32] bf16; XOR swizzle = b-swz ^ t-swz (R10).
    __shared__ alignas(16) unsigned short x_lds[(NT + 1) * BB * 32]; // 129 KB
    __shared__ alignas(16) unsigned short h_ring[RDEP][SLOT];        // 18 KB
    __shared__ int flag_sh;

    // ---------------- preamble ----------------
    if (tid == 0) flag_sh = 0;
    for (int e = tid; e < SLOT; e += 512) h_ring[RDEP - 1][e] = 0; // h(-1)=0
    // zero the x pad step
    x_lds[NT * BB * 32 + tid] = 0;

    // detect mask dtype: int32 {0,1} words are all <=1; byte-bools give words >1
    {
        const unsigned* mw = (const unsigned*)mask_pad;
        int f = 0;
        for (int e = tid; e < (NB * NT) / 4; e += 512) f |= (mw[e] > 1u) ? 1 : 0;
        if (f) atomicOr(&flag_sh, 1);
    }
    __syncthreads();
    const bool byteMode = (flag_sh != 0);

    // stage x (masked, bf16) into swizzled LDS: 16B writes, 16 iters/thread
    {
        const unsigned char* mb = (const unsigned char*)mask_pad;
        const int* mi = (const int*)mask_pad;
        #pragma unroll 4
        for (int it = 0; it < 16; ++it) {
            int u  = tid + it * 512;         // [b][t][k8] 8-elem block index
            int k8 = (u & 3) * 8;
            int t  = (u >> 2) & (NT - 1);
            int b  = u >> 9;
            bool mk = byteMode ? (mb[(b0 + b) * NT + t] != 0)
                               : (mi[(b0 + b) * NT + t] != 0);
            const float* src = x_raw + ((size_t)(b0 + b) * NT + t) * ND + k8;
            f32x4 xv0 = *(const f32x4*)(src);
            f32x4 xv1 = *(const f32x4*)(src + 4);
            uint4 pk = make_uint4(0, 0, 0, 0);
            if (mk) {
                pk.x = cvt_pk_bf16(xv0[0], xv0[1]);
                pk.y = cvt_pk_bf16(xv0[2], xv0[3]);
                pk.z = cvt_pk_bf16(xv1[0], xv1[1]);
                pk.w = cvt_pk_bf16(xv1[2], xv1[3]);
            }
            int eo = (t * (BB * 32) + b * 32 + k8)
                     ^ (((b >> 2) & 3) << 3) ^ ((t & 7) << 3);
            *(uint4*)&x_lds[eo] = pk;
        }
    }

    // ---- weight A-fragments in registers (loop-invariant), R13 packing ----
    // group 0 = {i,f} (gate base 0/64), group 1 = {g,o} (base 128/192).
    // Row slot s = l16: gate = (s>>1)&1, j_local = (s&1)|((s>>2)<<1).
    // Rows pre-scaled: g-rows (ga in [128,192)) by +2L, others by -L.
    bf16x8 aW0[2], aW1[2], aX[2];
    f32x4 cinit[2];
    {
        const float* Whh = W_hh + (size_t)d * NG * NH;
        const float* Wih = W_ih + (size_t)d * NG * (ND - 1);
        const int gateS = (l16 >> 1) & 1;
        const int jlocS = (l16 & 1) | ((l16 >> 2) << 1);
        #pragma unroll
        for (int g2 = 0; g2 < 2; ++g2) {
            int ga = g2 * 128 + gateS * 64 + w * 8 + jlocS;
            float s = ((ga >> 6) == 2) ? 2.0f * LOG2E : -LOG2E;
            f32x4 wa = *(const f32x4*)(Whh + ga * NH + grp * 8);
            f32x4 wb = *(const f32x4*)(Whh + ga * NH + grp * 8 + 4);
            f32x4 wc = *(const f32x4*)(Whh + ga * NH + 32 + grp * 8);
            f32x4 wd = *(const f32x4*)(Whh + ga * NH + 32 + grp * 8 + 4);
            #pragma unroll
            for (int e = 0; e < 4; ++e) {
                aW0[g2][e]     = (short)f2bf(s * wa[e]);
                aW0[g2][e + 4] = (short)f2bf(s * wb[e]);
                aW1[g2][e]     = (short)f2bf(s * wc[e]);
                aW1[g2][e + 4] = (short)f2bf(s * wd[e]);
            }
            #pragma unroll
            for (int e = 0; e < 8; ++e) {
                int j = grp * 8 + e;
                float vv = 0.0f;
                if (j != d) vv = Wih[ga * (ND - 1) + (j < d ? j : j - 1)];
                aX[g2][e] = (short)f2bf(s * vv);
            }
            // C-init (bias, pre-scaled): comp reg -> C row m = grp*4+reg
            #pragma unroll
            for (int reg = 0; reg < 4; ++reg) {
                int m  = grp * 4 + reg;
                int gr = g2 * 128 + ((m >> 1) & 1) * 64 + w * 8
                         + ((m & 1) | ((m >> 2) << 1));
                float ss = ((gr >> 6) == 2) ? 2.0f * LOG2E : -LOG2E;
                cinit[g2][reg] = ss * (b_ih[d * NG + gr] + b_hh[d * NG + gr]);
            }
        }
    }

    // packed-activation constants (register pairs, loop-invariant)
    // c'-prescale (R10): cell state kept as c' = 2*LOG2E*c, eC = exp2(c').
    const f32x2 kONE = {1.f, 1.f};
    const f32x2 kTL  = {2.0f * LOG2E, 2.0f * LOG2E};
    const f32x2 kN4L = {-4.0f * LOG2E, -4.0f * LOG2E};
    const f32x2 kN2  = {-2.f, -2.f};

    // flush-role constants: thread handles (ta_off, b, j-group of 8)
    const int f_ta = tid >> 7;          // 0..3
    const int f_b  = (tid >> 3) & 15;   // batch row
    const int f_jg = tid & 7;           // j-group
    float wout8[8];
    #pragma unroll
    for (int k = 0; k < 8; ++k) wout8[k] = W_out[d * NH + f_jg * 8 + k];
    const float bout = b_out[d];

    // ---- loop-invariant LDS/global pointers ----
    const unsigned short* hrd = &h_ring[0][l16 * HSTR + grp * 8];          // + slot*SLOT
    // this lane produces h for j = w*8 + 2*grp + {0,1} (comps {0,1} of accs)
    unsigned short*       hwr = &h_ring[0][l16 * HSTR + w * 8 + grp * 2];
    // x read base (elem index, pre-b-swz); R14: the 8 t-swizzled variants
    // hoisted into a statically-indexed table (U is compile-time per STEP).
    const int xbase = (l16 * 32 + grp * 8) ^ (((l16 >> 2) & 3) << 3);
    int xb[8];
    #pragma unroll
    for (int u = 0; u < 8; ++u) xb[u] = xbase ^ (u << 3);
    const unsigned short* xl  = x_lds;                                     // + tb*512
    const unsigned short* fp0 = &h_ring[4][f_b * HSTR + f_jg * 8];         // slots 4..7
    const unsigned short* fp1 = &h_ring[0][f_b * HSTR + f_jg * 8];         // slots 0..3
    float* outp = out + ((size_t)(b0 + f_b) * NT + f_ta) * ND + d;         // + ta0*ND

    f32x2 cpair = {0.f, 0.f};  // PRESCALED cell state c' = 2L*c
    uint4 fpre;                // FLUSH pre-read buffer (R12: read 1 step early)

    __syncthreads();   // x_lds + h_ring init ready (one-time full drain)

    // x-fragment register prefetch for step 0 (t=0: t-swz = 0)
    bf16x8 bxp = *(const bf16x8*)(xl + xb[0]);

// output projection from the pre-read register (R12): pure compute in the
// ds_read window. R14: quad-local reduce stages via DPP (VALU, no LDS);
// only the cross-quad xor4 remains a shuffle.
#define FLUSHR(TA0)                                                           \
    do {                                                                      \
        float p;                                                              \
        p = bf_lo(fpre.x) * wout8[0];                                        \
        p = __builtin_fmaf(bf_hi(fpre.x), wout8[1], p);                      \
        p = __builtin_fmaf(bf_lo(fpre.y), wout8[2], p);                      \
        p = __builtin_fmaf(bf_hi(fpre.y), wout8[3], p);                      \
        p = __builtin_fmaf(bf_lo(fpre.z), wout8[4], p);                      \
        p = __builtin_fmaf(bf_hi(fpre.z), wout8[5], p);                      \
        p = __builtin_fmaf(bf_lo(fpre.w), wout8[6], p);                      \
        p = __builtin_fmaf(bf_hi(fpre.w), wout8[7], p);                      \
        p = dpp_addf<0xB1>(p);   /* quad_perm [1,0,3,2] = xor1 */             \
        p = dpp_addf<0x4E>(p);   /* quad_perm [2,3,0,1] = xor2 */             \
        p += __shfl_xor(p, 4);                                               \
        if (f_jg == 0) outp[(size_t)(TA0) * ND] = p + bout;                  \
    } while (0)

// Step schedule (R10/R12-proven): issue h-reads (bh1 first), fill the LDS
// read window with FLUSHR (U==3/7, register-based) and the 2 all-register
// x-part MFMAs; gate MFMAs C-chain (full-rate) onto the x accumulators.
// R13: gates emerge pre-scaled in exp2 domain; extraction is reg aliasing.
#define STEP(U)                                                               \
    do {                                                                      \
        const bf16x8 bh1 = *(const bf16x8*)(hrd + (((U) + 7) & 7) * SLOT + 32);\
        const bf16x8 bh0 = *(const bf16x8*)(hrd + (((U) + 7) & 7) * SLOT);    \
        if ((U) == 2) fpre = *(const uint4*)(fp0 + f_ta * SLOT);              \
        if ((U) == 6) fpre = *(const uint4*)(fp1 + f_ta * SLOT);              \
        if ((U) == 3) { if (tb > 0) FLUSHR(tb - 4); }                         \
        if ((U) == 7) { FLUSHR(tb); }                                         \
        f32x4 aif, ago;                                                       \
        aif = __builtin_amdgcn_mfma_f32_16x16x32_bf16(aX[0], bxp, cinit[0], 0, 0, 0); \
        ago = __builtin_amdgcn_mfma_f32_16x16x32_bf16(aX[1], bxp, cinit[1], 0, 0, 0); \
        aif = __builtin_amdgcn_mfma_f32_16x16x32_bf16(aW1[0], bh1, aif, 0, 0, 0); \
        ago = __builtin_amdgcn_mfma_f32_16x16x32_bf16(aW1[1], bh1, ago, 0, 0, 0); \
        aif = __builtin_amdgcn_mfma_f32_16x16x32_bf16(aW0[0], bh0, aif, 0, 0, 0); \
        ago = __builtin_amdgcn_mfma_f32_16x16x32_bf16(aW0[1], bh0, ago, 0, 0, 0); \
        bxp = *(const bf16x8*)(xl + ((U) + 1) * 512 + xb[((U) + 1) & 7]);     \
        /* extraction = consecutive-pair aliasing (R13 packing):             \
           aif = {-L*i(j0), -L*i(j1), -L*f(j0), -L*f(j1)},                   \
           ago = {2L*g(j0), 2L*g(j1), -L*o(j0), -L*o(j1)} */                 \
        f32x2 eI = vexp2(lo2(aif));                                           \
        f32x2 eF = vexp2(hi2(aif));                                           \
        f32x2 eG = vexp2(lo2(ago));                                           \
        f32x2 eO = vexp2(hi2(ago));                                           \
        f32x2 Av = kONE + eI, Bv = kONE + eF;                                 \
        f32x2 Cv = kONE + eG, Dv = kONE + eO;                                 \
        f32x2 AB = Av * Bv, CD = Cv * Dv;                                     \
        f32x2 rab = vrcp(AB), rcd = vrcp(CD);                                 \
        f32x2 iv = rab * Bv, ff = rab * Av;                                   \
        /* tg2 = 2L*tanh(g) = fma(-4L, 1/(1+eG), 2L); rcd*Dv = 1/(1+eG) */    \
        f32x2 tg2 = vfma(kN4L, rcd * Dv, kTL);                                \
        f32x2 ov = rcd * Cv;                                                  \
        cpair = vfma(ff, cpair, iv * tg2);   /* c' = 2L*c */                  \
        f32x2 eC = vexp2(cpair);             /* exp2(2L*c) directly */        \
        f32x2 hv = ov * vfma(kN2, vrcp(kONE + eC), kONE);                     \
        *(unsigned*)(hwr + (U) * SLOT) = cvt_pk_bf16(hv.x, hv.y);             \
        asm volatile("s_waitcnt lgkmcnt(0)\n\ts_barrier" ::: "memory");       \
    } while (0)

    // ---------------- time loop: 16 outer iters x 8 static steps ----------
    for (int tb = 0; tb < NT; tb += 8) {
        STEP(0); STEP(1); STEP(2); STEP(3);
        STEP(4); STEP(5); STEP(6); STEP(7);
        xl += 8 * 512;
    }

    // epilogue flush: ta in [NT-4, NT-1] (slots 4..7; final barrier drained)
    {
        fpre = *(const uint4*)(fp0 + f_ta * SLOT);
        FLUSHR(NT - 4);
    }
#undef STEP
#undef FLUSHR
}

extern "C" void kernel_launch(void* const* d_in, const int* in_sizes, int n_in,
                              void* d_out, int out_size, void* d_ws, size_t ws_size,
                              hipStream_t stream) {
    const float* x_raw   = (const float*)d_in[0];
    const void*  mask_pad = d_in[1];
    const float* W_ih    = (const float*)d_in[2];
    const float* W_hh    = (const float*)d_in[3];
    const float* b_ih    = (const float*)d_in[4];
    const float* b_hh    = (const float*)d_in[5];
    const float* W_out   = (const float*)d_in[6];
    const float* b_out   = (const float*)d_in[7];
    float* out = (float*)d_out;

    dim3 grid(ND, NB / BB);
    lstm_imputer_kernel<<<grid, 512, 0, stream>>>(
        x_raw, mask_pad, W_ih, W_hh, b_ih, b_hh, W_out, b_out, out);
}

// Round 15
// 62.657 us; speedup vs baseline: 1.1846x; 1.0502x over previous
//
#include <hip/hip_runtime.h>
#include <hip/hip_bf16.h>

typedef __attribute__((ext_vector_type(8))) short bf16x8;
typedef __attribute__((ext_vector_type(4))) float f32x4;
typedef __attribute__((ext_vector_type(2))) float f32x2;

#define ND 32    // feature dim (independent LSTMs)
#define NH 64    // hidden
#define NB 128   // batch
#define NT 128   // time
#define NG 256   // 4*NH gates
#define BB 16    // batch rows per workgroup (batch = MFMA n-dim)
#define HSTR 72  // h ring row stride (elems): 144B, 16B-aligned rows
#define RDEP 8   // h ring depth; time loop unrolled by 8 -> static slots
#define SLOT (BB * HSTR)   // 1152 elems = 2304 B per ring slot
#define LOG2E 1.44269504f

__device__ __forceinline__ unsigned short f2bf(float f) {
    union { float f; unsigned u; } v; v.f = f;
    unsigned r = v.u + 0x7FFFu + ((v.u >> 16) & 1u);   // RNE
    return (unsigned short)(r >> 16);
}
// TRANS ops via compiler intrinsics ONLY (R2-R4 post-mortem: raw inline-asm
// v_exp/v_rcp hide the trans-result hazard from the backend -> schedule-
// dependent corruption. Intrinsics = backend owns hazard wait-states.)
__device__ __forceinline__ float fast_rcp(float x) {
    return __builtin_amdgcn_rcpf(x);
}
__device__ __forceinline__ float fast_exp2(float x) {   // 2^x
    return __builtin_amdgcn_exp2f(x);
}
__device__ __forceinline__ unsigned cvt_pk_bf16(float lo, float hi) {
    unsigned r; asm("v_cvt_pk_bf16_f32 %0, %1, %2" : "=v"(r) : "v"(lo), "v"(hi));
    return r;
}
__device__ __forceinline__ float bf_lo(unsigned u) {
    union { unsigned u; float f; } v; v.u = u << 16; return v.f;
}
__device__ __forceinline__ float bf_hi(unsigned u) {
    union { unsigned u; float f; } v; v.u = u & 0xffff0000u; return v.f;
}
// DPP quad-local butterfly add (xor1 / xor2 within quads): pure VALU — no
// LDS traffic, bit-identical to __shfl_xor(p,1/2).
template<int CTRL>
__device__ __forceinline__ float dpp_addf(float p) {
    union { float f; int i; } s, r;
    s.f = p;
    r.i = __builtin_amdgcn_update_dpp(s.i, s.i, CTRL, 0xF, 0xF, false);
    return p + r.f;
}

// ---- 2-lane float helpers, PURE C ext-vector ops (clang lowers +,* to
// v_pk_{add,mul}_f32 on gfx950). Trans ops are scalar intrinsics per lane.
__device__ __forceinline__ f32x2 vfma(f32x2 a, f32x2 b, f32x2 c) {
    f32x2 r;
    r.x = __builtin_fmaf(a.x, b.x, c.x);
    r.y = __builtin_fmaf(a.y, b.y, c.y);
    return r;
}
__device__ __forceinline__ f32x2 vexp2(f32x2 v) {
    f32x2 r; r.x = fast_exp2(v.x); r.y = fast_exp2(v.y); return r;
}
__device__ __forceinline__ f32x2 vrcp(f32x2 v) {
    f32x2 r; r.x = fast_rcp(v.x); r.y = fast_rcp(v.y); return r;
}
__device__ __forceinline__ f32x2 lo2(f32x4 v) {
    return __builtin_shufflevector(v, v, 0, 1);   // sub-register alias
}
__device__ __forceinline__ f32x2 hi2(f32x4 v) {
    return __builtin_shufflevector(v, v, 2, 3);   // sub-register alias
}

__global__ __launch_bounds__(512) void lstm_imputer_kernel(
    const float* __restrict__ x_raw,
    const void*  __restrict__ mask_pad,
    const float* __restrict__ W_ih,
    const float* __restrict__ W_hh,
    const float* __restrict__ b_ih,
    const float* __restrict__ b_hh,
    const float* __restrict__ W_out,
    const float* __restrict__ b_out,
    float* __restrict__ out)
{
    const int d   = blockIdx.x;        // feature / LSTM index
    const int b0  = blockIdx.y * BB;   // batch block
    const int tid = threadIdx.x;
    const int w    = tid >> 6;         // wave 0..7 = 8-j tile index
    const int lane = tid & 63;
    const int grp  = lane >> 4;        // k-fragment group
    const int l16  = lane & 15;        // batch col (MFMA n) / A row slot

    // R13 gate packing: A-row m holds gate = (m>>1)&1, j_local =
    // (m&1)|((m>>2)<<1). Acc comps {0,1} = gateA(j0,j1), {2,3} = gateB(j0,j1)
    // -> extraction is consecutive-VGPR aliasing. Rows pre-scaled by -L
    // (i,f,o) / +2L (g): MFMA emits gates already in exp2 domain.

    // x_lds[t][b][32] bf16; XOR swizzle = b-swz ^ t-swz (R10).
    __shared__ alignas(16) unsigned short x_lds[(NT + 1) * BB * 32]; // 129 KB
    __shared__ alignas(16) unsigned short h_ring[RDEP][SLOT];        // 18 KB
    __shared__ int flag_sh;

    // ---------------- preamble ----------------
    if (tid == 0) flag_sh = 0;
    for (int e = tid; e < SLOT; e += 512) h_ring[RDEP - 1][e] = 0; // h(-1)=0
    // zero the x pad step
    x_lds[NT * BB * 32 + tid] = 0;

    // detect mask dtype: int32 {0,1} words are all <=1; byte-bools give words >1
    {
        const unsigned* mw = (const unsigned*)mask_pad;
        int f = 0;
        for (int e = tid; e < (NB * NT) / 4; e += 512) f |= (mw[e] > 1u) ? 1 : 0;
        if (f) atomicOr(&flag_sh, 1);
    }
    __syncthreads();
    const bool byteMode = (flag_sh != 0);

    // stage x (masked, bf16) into swizzled LDS: 16B writes, 16 iters/thread
    {
        const unsigned char* mb = (const unsigned char*)mask_pad;
        const int* mi = (const int*)mask_pad;
        #pragma unroll 4
        for (int it = 0; it < 16; ++it) {
            int u  = tid + it * 512;         // [b][t][k8] 8-elem block index
            int k8 = (u & 3) * 8;
            int t  = (u >> 2) & (NT - 1);
            int b  = u >> 9;
            bool mk = byteMode ? (mb[(b0 + b) * NT + t] != 0)
                               : (mi[(b0 + b) * NT + t] != 0);
            const float* src = x_raw + ((size_t)(b0 + b) * NT + t) * ND + k8;
            f32x4 xv0 = *(const f32x4*)(src);
            f32x4 xv1 = *(const f32x4*)(src + 4);
            uint4 pk = make_uint4(0, 0, 0, 0);
            if (mk) {
                pk.x = cvt_pk_bf16(xv0[0], xv0[1]);
                pk.y = cvt_pk_bf16(xv0[2], xv0[3]);
                pk.z = cvt_pk_bf16(xv1[0], xv1[1]);
                pk.w = cvt_pk_bf16(xv1[2], xv1[3]);
            }
            int eo = (t * (BB * 32) + b * 32 + k8)
                     ^ (((b >> 2) & 3) << 3) ^ ((t & 7) << 3);
            *(uint4*)&x_lds[eo] = pk;
        }
    }

    // ---- weight A-fragments in registers (loop-invariant), R13 packing ----
    bf16x8 aW0[2], aW1[2], aX[2];
    f32x4 cinit[2];
    {
        const float* Whh = W_hh + (size_t)d * NG * NH;
        const float* Wih = W_ih + (size_t)d * NG * (ND - 1);
        const int gateS = (l16 >> 1) & 1;
        const int jlocS = (l16 & 1) | ((l16 >> 2) << 1);
        #pragma unroll
        for (int g2 = 0; g2 < 2; ++g2) {
            int ga = g2 * 128 + gateS * 64 + w * 8 + jlocS;
            float s = ((ga >> 6) == 2) ? 2.0f * LOG2E : -LOG2E;
            f32x4 wa = *(const f32x4*)(Whh + ga * NH + grp * 8);
            f32x4 wb = *(const f32x4*)(Whh + ga * NH + grp * 8 + 4);
            f32x4 wc = *(const f32x4*)(Whh + ga * NH + 32 + grp * 8);
            f32x4 wd = *(const f32x4*)(Whh + ga * NH + 32 + grp * 8 + 4);
            #pragma unroll
            for (int e = 0; e < 4; ++e) {
                aW0[g2][e]     = (short)f2bf(s * wa[e]);
                aW0[g2][e + 4] = (short)f2bf(s * wb[e]);
                aW1[g2][e]     = (short)f2bf(s * wc[e]);
                aW1[g2][e + 4] = (short)f2bf(s * wd[e]);
            }
            #pragma unroll
            for (int e = 0; e < 8; ++e) {
                int j = grp * 8 + e;
                float vv = 0.0f;
                if (j != d) vv = Wih[ga * (ND - 1) + (j < d ? j : j - 1)];
                aX[g2][e] = (short)f2bf(s * vv);
            }
            // C-init (bias, pre-scaled): comp reg -> C row m = grp*4+reg
            #pragma unroll
            for (int reg = 0; reg < 4; ++reg) {
                int m  = grp * 4 + reg;
                int gr = g2 * 128 + ((m >> 1) & 1) * 64 + w * 8
                         + ((m & 1) | ((m >> 2) << 1));
                float ss = ((gr >> 6) == 2) ? 2.0f * LOG2E : -LOG2E;
                cinit[g2][reg] = ss * (b_ih[d * NG + gr] + b_hh[d * NG + gr]);
            }
        }
    }

    // packed-activation constants (register pairs, loop-invariant)
    // c'-prescale (R10): cell state kept as c' = 2*LOG2E*c, eC = exp2(c').
    const f32x2 kONE = {1.f, 1.f};
    const f32x2 kTL  = {2.0f * LOG2E, 2.0f * LOG2E};
    const f32x2 kNTL = {-2.0f * LOG2E, -2.0f * LOG2E};
    const f32x2 kN2  = {-2.f, -2.f};

    // flush-role constants: thread handles (ta_off, b, j-group of 8)
    const int f_ta = tid >> 7;          // 0..3
    const int f_b  = (tid >> 3) & 15;   // batch row
    const int f_jg = tid & 7;           // j-group
    float wout8[8];
    #pragma unroll
    for (int k = 0; k < 8; ++k) wout8[k] = W_out[d * NH + f_jg * 8 + k];
    const float bout = b_out[d];

    // ---- loop-invariant LDS/global pointers ----
    const unsigned short* hrd = &h_ring[0][l16 * HSTR + grp * 8];          // + slot*SLOT
    unsigned short*       hwr = &h_ring[0][l16 * HSTR + w * 8 + grp * 2];
    // x read base; the 8 t-swizzled variants hoisted (static index per STEP)
    const int xbase = (l16 * 32 + grp * 8) ^ (((l16 >> 2) & 3) << 3);
    int xb[8];
    #pragma unroll
    for (int u = 0; u < 8; ++u) xb[u] = xbase ^ (u << 3);
    const unsigned short* xl  = x_lds;                                     // + tb*512
    const unsigned short* fp0 = &h_ring[4][f_b * HSTR + f_jg * 8];         // slots 4..7
    const unsigned short* fp1 = &h_ring[0][f_b * HSTR + f_jg * 8];         // slots 0..3
    float* outp = out + ((size_t)(b0 + f_b) * NT + f_ta) * ND + d;         // + ta0*ND

    f32x2 cpair = {0.f, 0.f};  // PRESCALED cell state c' = 2L*c
    uint4 fpre;                // FLUSH pre-read buffer (R12: read 1 step early)

    __syncthreads();   // x_lds + h_ring init ready (one-time full drain)

    // x-fragment register prefetch for step 0 (t=0: t-swz = 0)
    bf16x8 bxp = *(const bf16x8*)(xl + xb[0]);

// output projection from the pre-read register (R12/R14): pure compute in
// the ds_read window; quad-local reduce via DPP, cross-quad via shfl_xor(4).
#define FLUSHR(TA0)                                                           \
    do {                                                                      \
        float p;                                                              \
        p = bf_lo(fpre.x) * wout8[0];                                        \
        p = __builtin_fmaf(bf_hi(fpre.x), wout8[1], p);                      \
        p = __builtin_fmaf(bf_lo(fpre.y), wout8[2], p);                      \
        p = __builtin_fmaf(bf_hi(fpre.y), wout8[3], p);                      \
        p = __builtin_fmaf(bf_lo(fpre.z), wout8[4], p);                      \
        p = __builtin_fmaf(bf_hi(fpre.z), wout8[5], p);                      \
        p = __builtin_fmaf(bf_lo(fpre.w), wout8[6], p);                      \
        p = __builtin_fmaf(bf_hi(fpre.w), wout8[7], p);                      \
        p = dpp_addf<0xB1>(p);   /* quad_perm [1,0,3,2] = xor1 */             \
        p = dpp_addf<0x4E>(p);   /* quad_perm [2,3,0,1] = xor2 */             \
        p += __shfl_xor(p, 4);                                               \
        if (f_jg == 0) outp[(size_t)(TA0) * ND] = p + bout;                  \
    } while (0)

// Step schedule (R10/R12-proven): issue h-reads (bh1 first), fill the LDS
// read window with FLUSHR (U==3/7) and the 2 all-register x-part MFMAs;
// gate MFMAs C-chain (full-rate) onto the x accumulators.
// R15 activation: sig(i)*tanh(g) = (eG-1)/((1+eI)(1+eG)) via ONE rcp;
// sig(f),sig(o) share rcp(B*D); tail hv = fma(-2ov, rcp(1+eC), ov).
// 14 packed VALU + 8 trans per pair (was 16+8); chain ~3 ops shorter.
#define STEP(U)                                                               \
    do {                                                                      \
        const bf16x8 bh1 = *(const bf16x8*)(hrd + (((U) + 7) & 7) * SLOT + 32);\
        const bf16x8 bh0 = *(const bf16x8*)(hrd + (((U) + 7) & 7) * SLOT);    \
        if ((U) == 2) fpre = *(const uint4*)(fp0 + f_ta * SLOT);              \
        if ((U) == 6) fpre = *(const uint4*)(fp1 + f_ta * SLOT);              \
        if ((U) == 3) { if (tb > 0) FLUSHR(tb - 4); }                         \
        if ((U) == 7) { FLUSHR(tb); }                                         \
        f32x4 aif, ago;                                                       \
        aif = __builtin_amdgcn_mfma_f32_16x16x32_bf16(aX[0], bxp, cinit[0], 0, 0, 0); \
        ago = __builtin_amdgcn_mfma_f32_16x16x32_bf16(aX[1], bxp, cinit[1], 0, 0, 0); \
        aif = __builtin_amdgcn_mfma_f32_16x16x32_bf16(aW1[0], bh1, aif, 0, 0, 0); \
        ago = __builtin_amdgcn_mfma_f32_16x16x32_bf16(aW1[1], bh1, ago, 0, 0, 0); \
        aif = __builtin_amdgcn_mfma_f32_16x16x32_bf16(aW0[0], bh0, aif, 0, 0, 0); \
        ago = __builtin_amdgcn_mfma_f32_16x16x32_bf16(aW0[1], bh0, ago, 0, 0, 0); \
        bxp = *(const bf16x8*)(xl + ((U) + 1) * 512 + xb[((U) + 1) & 7]);     \
        /* aif = {-i,-i,-f,-f}*L, ago = {2Lg, 2Lg, -Lo, -Lo} (R13 packing) */ \
        f32x2 eI = vexp2(lo2(aif));    /* e^-i */                             \
        f32x2 eF = vexp2(hi2(aif));    /* e^-f */                             \
        f32x2 eG = vexp2(lo2(ago));    /* e^2g */                             \
        f32x2 eO = vexp2(hi2(ago));    /* e^-o */                             \
        f32x2 Av = kONE + eI, Bv = kONE + eF;                                 \
        f32x2 Cv = kONE + eG, Dv = kONE + eO;                                 \
        f32x2 sg = vfma(kTL, eG, kNTL);     /* 2L*(eG-1) */                   \
        f32x2 AC = Av * Cv, BD = Bv * Dv;                                     \
        f32x2 rac = vrcp(AC), rbd = vrcp(BD);                                 \
        f32x2 ig2 = sg * rac;               /* 2L*sig(i)*tanh(g) */           \
        f32x2 ff  = rbd * Dv;               /* sig(f) */                      \
        f32x2 ov  = rbd * Bv;               /* sig(o) */                      \
        f32x2 n2ov = kN2 * ov;                                                \
        cpair = vfma(ff, cpair, ig2);       /* c' = 2L*c */                   \
        f32x2 eC = vexp2(cpair);            /* e^2c */                        \
        f32x2 rE = vrcp(kONE + eC);                                           \
        f32x2 hv = vfma(n2ov, rE, ov);      /* sig(o)*tanh(c) */              \
        *(unsigned*)(hwr + (U) * SLOT) = cvt_pk_bf16(hv.x, hv.y);             \
        asm volatile("s_waitcnt lgkmcnt(0)\n\ts_barrier" ::: "memory");       \
    } while (0)

    // ---------------- time loop: 16 outer iters x 8 static steps ----------
    for (int tb = 0; tb < NT; tb += 8) {
        STEP(0); STEP(1); STEP(2); STEP(3);
        STEP(4); STEP(5); STEP(6); STEP(7);
        xl += 8 * 512;
    }

    // epilogue flush: ta in [NT-4, NT-1] (slots 4..7; final barrier drained)
    {
        fpre = *(const uint4*)(fp0 + f_ta * SLOT);
        FLUSHR(NT - 4);
    }
#undef STEP
#undef FLUSHR
}

extern "C" void kernel_launch(void* const* d_in, const int* in_sizes, int n_in,
                              void* d_out, int out_size, void* d_ws, size_t ws_size,
                              hipStream_t stream) {
    const float* x_raw   = (const float*)d_in[0];
    const void*  mask_pad = d_in[1];
    const float* W_ih    = (const float*)d_in[2];
    const float* W_hh    = (const float*)d_in[3];
    const float* b_ih    = (const float*)d_in[4];
    const float* b_hh    = (const float*)d_in[5];
    const float* W_out   = (const float*)d_in[6];
    const float* b_out   = (const float*)d_in[7];
    float* out = (float*)d_out;

    dim3 grid(ND, NB / BB);
    lstm_imputer_kernel<<<grid, 512, 0, stream>>>(
        x_raw, mask_pad, W_ih, W_hh, b_ih, b_hh, W_out, b_out, out);
}